// Round 1
// 552.872 us; speedup vs baseline: 1.5333x; 1.5333x over previous
//
#include <hip/hip_runtime.h>
#include <hip/hip_fp16.h>
#include <cstdint>
#include <cstddef>

#define NN 50000      // nodes
#define NE 800000     // edges per path
#define NP 4          // metapaths
#define DD 256        // d_in = d_out
#define HH 128        // attention hidden
#define MPAD 50048    // NN rounded up to 64 (782*64)

#define NB 196        // node buckets of 256 nodes: ceil(50000/256)
#define CAP 5120      // slots per (path,bucket); mean 4096, sigma ~64 -> >8 sigma margin
#define EPB 4096      // edges per bin block
#define NBB ((NE + EPB - 1) / EPB)   // 196 bin blocks per path
#define BIN_BLOCKS (NBB * NP)        // 784

typedef _Float16 f16x8 __attribute__((ext_vector_type(8)));
typedef float f32x4 __attribute__((ext_vector_type(4)));

#define X_OCT (NN * DD / 8)        // 1,600,000
#define W_OCT (NP * DD * DD / 8)   // 32,768
#define W1_OCT (HH * DD / 8)       // 4,096
#define CVT_BLOCKS ((X_OCT + W_OCT + W1_OCT + 255) / 256)     // 6394
#define GEMM_BLOCKS ((MPAD / 64) * NP)                        // 3128

// ---------------- k1: edge bucket-binning (pass 1) ∥ fp32->f16 converts -----
// Bin blocks: 4096 edges each. LDS histogram over 196 dst-buckets, ONE global
// returning atomic per (block,bucket) reserves space, LDS reorder, then
// bucket-contiguous (coalesced) write of packed (bucket|ldst|src) words.
// Replaces 3.2M scattered returning atomics + 3.2M scattered 4B stores.
__global__ __launch_bounds__(256) void k_bin(const int* __restrict__ edges,
                                             int* __restrict__ gcnt,            // [NP*NB]
                                             unsigned int* __restrict__ binned, // [NP*NB][CAP]
                                             const float* __restrict__ x,
                                             const float* __restrict__ Ws,
                                             const float* __restrict__ w1,
                                             _Float16* __restrict__ xh,
                                             _Float16* __restrict__ Wt,
                                             _Float16* __restrict__ w1t) {
    const int bx = blockIdx.x;
    const int tid = threadIdx.x;
    if (bx < BIN_BLOCKS) {
        __shared__ int hist[256], lb[256], cur[256], gbase[256], wsum[4];
        __shared__ unsigned int stage[EPB];
        const int p  = bx / NBB;
        const int bc = bx - p * NBB;
        const int e0 = bc * EPB;
        const int total = min(EPB, NE - e0);
        const int* es = edges + (size_t)p * 2 * NE;       // srcs
        const int* ed = es + NE;                          // dsts
        hist[tid] = 0;
        __syncthreads();
        unsigned int word[16];
        int bkt[16];
#pragma unroll
        for (int j = 0; j < 16; j++) {
            int e = e0 + j * 256 + tid;
            bkt[j] = -1;
            if (e < NE) {
                int dst = ed[e];
                int src = es[e];
                int b = dst >> 8;                          // 0..195
                bkt[j] = b;
                word[j] = ((unsigned)b << 24) | ((unsigned)(dst & 255) << 16) | (unsigned)src;
                atomicAdd(&hist[b], 1);
            }
        }
        __syncthreads();
        // exclusive scan of hist[0..255]
        const int lane = tid & 63, wv = tid >> 6;
        int v = hist[tid];
        int incl = v;
#pragma unroll
        for (int off = 1; off < 64; off <<= 1) {
            int u = __shfl_up(incl, off);
            if (lane >= off) incl += u;
        }
        if (lane == 63) wsum[wv] = incl;
        __syncthreads();
        int wbase = 0;
        for (int i = 0; i < wv; i++) wbase += wsum[i];
        int excl = wbase + incl - v;
        lb[tid] = excl;
        cur[tid] = excl;
        if (tid < NB && v > 0) gbase[tid] = atomicAdd(&gcnt[p * NB + tid], v);
        __syncthreads();
        // LDS reorder by bucket
#pragma unroll
        for (int j = 0; j < 16; j++)
            if (bkt[j] >= 0) {
                int r = atomicAdd(&cur[bkt[j]], 1);
                stage[r] = word[j];
            }
        __syncthreads();
        // coalesced-ish write out: runs of same bucket are contiguous
        for (int s = tid; s < total; s += 256) {
            unsigned int wd = stage[s];
            int b = wd >> 24;
            int posl = gbase[b] + (s - lb[b]);
            if (posl < CAP)
                binned[(size_t)(p * NB + b) * CAP + posl] = wd & 0x00FFFFFFu;
        }
        return;
    }
    // ---- converts ----
    int i = (bx - BIN_BLOCKS) * 256 + tid;
    if (i < X_OCT) {
        const float4* src = (const float4*)x + (size_t)i * 2;
        float4 v0 = src[0], v1 = src[1];
        f16x8 o;
        o[0] = (_Float16)v0.x; o[1] = (_Float16)v0.y; o[2] = (_Float16)v0.z; o[3] = (_Float16)v0.w;
        o[4] = (_Float16)v1.x; o[5] = (_Float16)v1.y; o[6] = (_Float16)v1.z; o[7] = (_Float16)v1.w;
        *((f16x8*)xh + i) = o;
    } else if (i < X_OCT + W_OCT) {
        int j = i - X_OCT;                 // (p, n, k-octet)
        int p   = j / (DD * DD / 8);
        int rem = j - p * (DD * DD / 8);
        int n   = rem >> 5;
        int k8  = (rem & 31) * 8;
        const float* wp = Ws + (size_t)p * DD * DD;
        f16x8 o;
#pragma unroll
        for (int t = 0; t < 8; t++) o[t] = (_Float16)wp[(size_t)(k8 + t) * DD + n];
        *((f16x8*)(Wt + (size_t)p * DD * DD + (size_t)n * DD + k8)) = o;
    } else if (i < X_OCT + W_OCT + W1_OCT) {
        int j = i - X_OCT - W_OCT;         // (n, k-octet)
        int n  = j >> 5;
        int k8 = (j & 31) * 8;
        f16x8 o;
#pragma unroll
        for (int t = 0; t < 8; t++) o[t] = (_Float16)w1[(size_t)(k8 + t) * HH + n];
        *((f16x8*)(w1t + (size_t)n * DD + k8)) = o;
    }
}

// ---------------- k_sort (pass 2): per-bucket LDS counting sort -------------
// One block per (path,bucket). Produces per-node degree -> dinv, absolute CSR
// offs/ends, and fully coalesced ushort srcs write-out. No global atomics.
__global__ __launch_bounds__(256) void k_sort(const int* __restrict__ gcnt,
                                              const unsigned int* __restrict__ binned,
                                              unsigned short* __restrict__ srcs,
                                              int* __restrict__ offs,
                                              int* __restrict__ ends,
                                              float* __restrict__ dinv) {
    __shared__ int hist[256], cur[256], wsum[4];
    __shared__ unsigned short sorted[CAP];
    const int bx = blockIdx.x;            // p*NB + b
    const int tid = threadIdx.x;
    const int p = bx / NB, b = bx - p * NB;
    const size_t base = (size_t)bx * CAP;
    const int n = min(gcnt[bx], CAP);
    hist[tid] = 0;
    __syncthreads();
    unsigned int w[20];                   // CAP/256 = 20
#pragma unroll
    for (int j = 0; j < 20; j++) {
        int s = j * 256 + tid;
        w[j] = 0xFFFFFFFFu;
        if (s < n) {
            w[j] = binned[base + s];
            atomicAdd(&hist[(w[j] >> 16) & 255], 1);
        }
    }
    __syncthreads();
    const int lane = tid & 63, wv = tid >> 6;
    int v = hist[tid];
    int incl = v;
#pragma unroll
    for (int off = 1; off < 64; off <<= 1) {
        int u = __shfl_up(incl, off);
        if (lane >= off) incl += u;
    }
    if (lane == 63) wsum[wv] = incl;
    __syncthreads();
    int wbase = 0;
    for (int i = 0; i < wv; i++) wbase += wsum[i];
    int excl = wbase + incl - v;
    cur[tid] = excl;
    const int node = b * 256 + tid;
    if (node < NN) {
        int o = (int)base + excl;
        offs[p * NN + node] = o;
        ends[p * NN + node] = o + v;
        dinv[p * NN + node] = rsqrtf((float)v + 1.0f);
    }
    __syncthreads();
#pragma unroll
    for (int j = 0; j < 20; j++)
        if (w[j] != 0xFFFFFFFFu) {
            int r = atomicAdd(&cur[(w[j] >> 16) & 255], 1);
            sorted[r] = (unsigned short)(w[j] & 0xFFFFu);
        }
    __syncthreads();
#pragma unroll
    for (int j = 0; j < 20; j++) {
        int s = j * 256 + tid;
        if (s < n) srcs[base + s] = sorted[s];
    }
}

// ---------------- k_gemm: xws = f16(dinv * (xh @ W)) ------------------------
__global__ __launch_bounds__(256) void k_gemm(const _Float16* __restrict__ xh,  // [MPAD][256]
                                              const _Float16* __restrict__ Wt,  // [NP][256 n][256 k]
                                              const float* __restrict__ dinv,   // [NP][NN]
                                              _Float16* __restrict__ xws) {     // [NP][NN][256]
    const int gb   = blockIdx.x;
    const int p    = gb / (MPAD / 64);
    const int bm   = gb - p * (MPAD / 64);
    const int wv   = threadIdx.x >> 6;
    const int lane = threadIdx.x & 63;
    const int m_base = bm * 64;
    const int n0   = wv * 64;
    const int mr   = lane & 15;
    const int quad = lane >> 4;

    const _Float16* ap = xh + (size_t)(m_base + mr) * DD + quad * 8;
    const _Float16* bp = Wt + (size_t)p * DD * DD + (size_t)(n0 + mr) * DD + quad * 8;
    const float* dv = dinv + (size_t)p * NN;
    _Float16* cp = xws + (size_t)p * NN * DD;

    f32x4 acc[4][4] = {};   // [m-tile][n-tile]
    for (int k0 = 0; k0 < DD; k0 += 32) {
        f16x8 a[4], b[4];
#pragma unroll
        for (int i = 0; i < 4; i++) a[i] = *(const f16x8*)(ap + (size_t)i * 16 * DD + k0);
#pragma unroll
        for (int j = 0; j < 4; j++) b[j] = *(const f16x8*)(bp + (size_t)j * 16 * DD + k0);
#pragma unroll
        for (int i = 0; i < 4; i++)
#pragma unroll
            for (int j = 0; j < 4; j++)
                acc[i][j] = __builtin_amdgcn_mfma_f32_16x16x32_f16(a[i], b[j], acc[i][j], 0, 0, 0);
    }
#pragma unroll
    for (int i = 0; i < 4; i++) {
#pragma unroll
        for (int r = 0; r < 4; r++) {
            int row = m_base + i * 16 + quad * 4 + r;
            if (row < NN) {
                float d = dv[row];
#pragma unroll
                for (int j = 0; j < 4; j++)
                    cp[(size_t)row * DD + n0 + j * 16 + mr] = (_Float16)(d * acc[i][j][r]);
            }
        }
    }
}

// ---------------- fused gather + bias + MFMA semantic attention -------------
// 512 threads = 8 waves; block handles 16 nodes (64 z-rows in LDS, 33.8 KB).
__global__ __launch_bounds__(512) void k_fused(const _Float16* __restrict__ xws, // [NP][NN][256] dinv-scaled f16
                                               const float* __restrict__ dinv,   // [NP][NN]
                                               const int* __restrict__ offs,     // [NP][NN] absolute
                                               const int* __restrict__ ends,     // [NP][NN] absolute
                                               const unsigned short* __restrict__ srcs, // global sorted
                                               const float* __restrict__ bs,     // [NP][256]
                                               const _Float16* __restrict__ w1t, // [128 n][256 k] f16
                                               const float* __restrict__ b1,     // [128]
                                               const float* __restrict__ w2,     // [128]
                                               float* __restrict__ out) {        // [NN][256]
    const int w    = threadIdx.x >> 6;   // 0..7
    const int lane = threadIdx.x & 63;
    const int quad = lane >> 4, mr = lane & 15;
    const int half = lane >> 5, hl = lane & 31;

    // row stride 264 halves = 528 B keeps f16x8 accesses 16B-aligned.
    __shared__ __align__(16) _Float16 zs[64][264];

    union U { f16x8 v; int i4[4]; };

    // ---- gather: z[row] = dinv*(self + sum_src xws[src]) + bias, row=(node,path)
#pragma unroll 1
    for (int q = 0; q < 2; q++) {
        const int n = blockIdx.x * 16 + w * 2 + q;
#pragma unroll 1
        for (int p = 0; p < NP; p++) {
            const _Float16* xp = xws + (size_t)p * NN * DD;
            U acc;
#pragma unroll
            for (int t = 0; t < 4; t++) acc.i4[t] = 0;
            if (half == 0)
                acc.v = *(const f16x8*)(xp + (size_t)n * DD + hl * 8);  // self loop
            int k  = offs[p * NN + n];
            int ke = ends[p * NN + n];
            for (; k + 8 <= ke; k += 8) {
                int s0 = srcs[k + half];
                int s1 = srcs[k + 2 + half];
                int s2 = srcs[k + 4 + half];
                int s3 = srcs[k + 6 + half];
                f16x8 v0 = *(const f16x8*)(xp + (size_t)s0 * DD + hl * 8);
                f16x8 v1 = *(const f16x8*)(xp + (size_t)s1 * DD + hl * 8);
                f16x8 v2 = *(const f16x8*)(xp + (size_t)s2 * DD + hl * 8);
                f16x8 v3 = *(const f16x8*)(xp + (size_t)s3 * DD + hl * 8);
                acc.v += (v0 + v1) + (v2 + v3);
            }
            for (; k + 2 <= ke; k += 2) {
                int s0 = srcs[k + half];
                acc.v += *(const f16x8*)(xp + (size_t)s0 * DD + hl * 8);
            }
            if (k < ke && half == 0)
                acc.v += *(const f16x8*)(xp + (size_t)srcs[k] * DD + hl * 8);
            // combine even/odd halves
            U other;
#pragma unroll
            for (int t = 0; t < 4; t++) other.i4[t] = __shfl_xor(acc.i4[t], 32);
            acc.v += other.v;
            if (half == 0) {
                float dvv = dinv[p * NN + n];
                int row = (w * 2 + q) * 4 + p;
                f16x8 zo;
#pragma unroll
                for (int t = 0; t < 8; t++)
                    zo[t] = (_Float16)(dvv * (float)acc.v[t] + bs[p * DD + hl * 8 + t]);
                *(f16x8*)&zs[row][hl * 8] = zo;
            }
        }
    }

    __syncthreads();
    if (w >= 4) return;   // attention/combine handled by waves 0-3 (16 rows each)

    // ---- attention MFMA: H(16x128) = Z_rows(16x256) @ w1t(128x256)^T per wave
    f32x4 acch[8] = {};
    for (int k0 = 0; k0 < DD; k0 += 32) {
        f16x8 a = *(const f16x8*)&zs[w * 16 + mr][k0 + quad * 8];
#pragma unroll
        for (int j = 0; j < 8; j++) {
            f16x8 b = *(const f16x8*)(w1t + (size_t)(j * 16 + mr) * DD + k0 + quad * 8);
            acch[j] = __builtin_amdgcn_mfma_f32_16x16x32_f16(a, b, acch[j], 0, 0, 0);
        }
    }

    // ---- scores: s[path] = sum_col tanh(h + b1[col]) * w2[col]
    float part[4] = {};
#pragma unroll
    for (int j = 0; j < 8; j++) {
        int col = j * 16 + mr;
        float bb = b1[col], ww = w2[col];
#pragma unroll
        for (int r = 0; r < 4; r++)
            part[r] += tanhf(acch[j][r] + bb) * ww;
    }
#pragma unroll
    for (int off = 1; off < 16; off <<= 1) {
#pragma unroll
        for (int r = 0; r < 4; r++) part[r] += __shfl_xor(part[r], off);
    }
    float m = fmaxf(fmaxf(part[0], part[1]), fmaxf(part[2], part[3]));
    float e0 = __expf(part[0] - m), e1 = __expf(part[1] - m),
          e2 = __expf(part[2] - m), e3 = __expf(part[3] - m);
    float rr = 1.0f / (e0 + e1 + e2 + e3);
    float be[4] = {e0 * rr, e1 * rr, e2 * rr, e3 * rr};

    // ---- combine: lane handles node (w*4+quad), cols [mr*16, mr*16+16)
    const int n  = blockIdx.x * 16 + w * 4 + quad;
    const int rb = w * 16 + quad * 4;
    float o[16] = {};
#pragma unroll
    for (int p = 0; p < 4; p++) {
        f16x8 z0 = *(const f16x8*)&zs[rb + p][mr * 16];
        f16x8 z1 = *(const f16x8*)&zs[rb + p][mr * 16 + 8];
#pragma unroll
        for (int t = 0; t < 8; t++) {
            o[t]     += be[p] * (float)z0[t];
            o[t + 8] += be[p] * (float)z1[t];
        }
    }
#pragma unroll
    for (int t = 0; t < 16; t += 4)
        *(float4*)(out + (size_t)n * DD + mr * 16 + t) =
            make_float4(o[t], o[t + 1], o[t + 2], o[t + 3]);
}

extern "C" void kernel_launch(void* const* d_in, const int* in_sizes, int n_in,
                              void* d_out, int out_size, void* d_ws, size_t ws_size,
                              hipStream_t stream) {
    const float* x     = (const float*)d_in[0];
    const int*   edges = (const int*)d_in[1];   // [4][2][800000]
    const float* Ws    = (const float*)d_in[2]; // [4][256][256]
    const float* bs    = (const float*)d_in[3]; // [4][256]
    const float* w1    = (const float*)d_in[4]; // [256][128]
    const float* b1    = (const float*)d_in[5]; // [128]
    const float* w2    = (const float*)d_in[6]; // [128]
    float* out = (float*)d_out;

    char* ws = (char*)d_ws;
    int*            gcnt   = (int*)ws;                          // 3.1 KB
    unsigned int*   binned = (unsigned int*)(ws + (1 << 20));   // 784*5120*4 = 16.06 MB
    unsigned short* srcs   = (unsigned short*)(ws + (18 << 20));// 8.03 MB
    float*          dinv   = (float*)(ws + (27 << 20));         // 800 KB
    int*            offs   = (int*)(ws + (28 << 20));           // 800 KB
    int*            ends   = (int*)(ws + (29 << 20));           // 800 KB
    _Float16*       Wt     = (_Float16*)(ws + (30 << 20));      // 512 KB
    _Float16*       w1t    = (_Float16*)(ws + (30 << 20) + (1 << 19)); // 64 KB
    _Float16*       xh     = (_Float16*)(ws + (31 << 20));      // 24.4 MB (MPAD rows)
    _Float16*       xws    = (_Float16*)(ws + (57 << 20));      // 97.7 MB -> total ~155 MB

    hipMemsetAsync(gcnt, 0, NP * NB * sizeof(int), stream);

    k_bin<<<BIN_BLOCKS + CVT_BLOCKS, 256, 0, stream>>>(
        edges, gcnt, binned, x, Ws, w1, xh, Wt, w1t);

    k_sort<<<NP * NB, 256, 0, stream>>>(gcnt, binned, srcs, offs, ends, dinv);

    k_gemm<<<GEMM_BLOCKS, 256, 0, stream>>>(xh, Wt, dinv, xws);

    k_fused<<<NN / 16, 512, 0, stream>>>(xws, dinv, offs, ends, srcs,
                                         bs, w1t, b1, w2, out);
}

// Round 2
// 539.645 us; speedup vs baseline: 1.5709x; 1.0245x over previous
//
#include <hip/hip_runtime.h>
#include <hip/hip_fp16.h>
#include <cstdint>
#include <cstddef>

#define NN 50000      // nodes
#define NE 800000     // edges per path
#define NP 4          // metapaths
#define DD 256        // d_in = d_out
#define HH 128        // attention hidden
#define MPAD 50048    // NN rounded up to 64 (782*64)
#define PADIDX 50000  // zero-row index used for CSR padding (row is all-zeros in xws)

#define NB 196        // node buckets of 256 nodes: ceil(50000/256)
#define CAP 5120      // binned slots per (path,bucket); mean 4096, sigma ~64
#define SCAP 6144     // srcs slots per (path,bucket); mean 4992 after pad-to-8, ~12 sigma
#define EPB 4096      // edges per bin block
#define NBB ((NE + EPB - 1) / EPB)   // 196 bin blocks per path
#define BIN_BLOCKS (NBB * NP)        // 784

typedef _Float16 f16x8 __attribute__((ext_vector_type(8)));
typedef float f32x4 __attribute__((ext_vector_type(4)));

#define X_OCT (NN * DD / 8)        // 1,600,000 real x octets
#define XP_OCT (MPAD * DD / 8)     // 1,601,536 (pad rows zeroed)
#define W_OCT (NP * DD * DD / 8)   // 32,768
#define W1_OCT (HH * DD / 8)       // 4,096
#define CVT_BLOCKS ((XP_OCT + W_OCT + W1_OCT + 255) / 256)    // 6400
#define GEMM_BLOCKS ((MPAD / 64) * NP)                        // 3128

// ---------------- k1: edge bucket-binning (pass 1) ∥ fp32->f16 converts -----
__global__ __launch_bounds__(256) void k_bin(const int* __restrict__ edges,
                                             int* __restrict__ gcnt,            // [NP*NB]
                                             unsigned int* __restrict__ binned, // [NP*NB][CAP]
                                             const float* __restrict__ x,
                                             const float* __restrict__ Ws,
                                             const float* __restrict__ w1,
                                             _Float16* __restrict__ xh,
                                             _Float16* __restrict__ Wt,
                                             _Float16* __restrict__ w1t) {
    const int bx = blockIdx.x;
    const int tid = threadIdx.x;
    if (bx < BIN_BLOCKS) {
        __shared__ int hist[256], lb[256], cur[256], gbase[256], wsum[4];
        __shared__ unsigned int stage[EPB];
        const int p  = bx / NBB;
        const int bc = bx - p * NBB;
        const int e0 = bc * EPB;
        const int total = min(EPB, NE - e0);
        const int* es = edges + (size_t)p * 2 * NE;       // srcs
        const int* ed = es + NE;                          // dsts
        hist[tid] = 0;
        __syncthreads();
        unsigned int word[16];
        int bkt[16];
#pragma unroll
        for (int j = 0; j < 16; j++) {
            int e = e0 + j * 256 + tid;
            bkt[j] = -1;
            if (e < NE) {
                int dst = ed[e];
                int src = es[e];
                int b = dst >> 8;                          // 0..195
                bkt[j] = b;
                word[j] = ((unsigned)b << 24) | ((unsigned)(dst & 255) << 16) | (unsigned)src;
                atomicAdd(&hist[b], 1);
            }
        }
        __syncthreads();
        // exclusive scan of hist[0..255]
        const int lane = tid & 63, wv = tid >> 6;
        int v = hist[tid];
        int incl = v;
#pragma unroll
        for (int off = 1; off < 64; off <<= 1) {
            int u = __shfl_up(incl, off);
            if (lane >= off) incl += u;
        }
        if (lane == 63) wsum[wv] = incl;
        __syncthreads();
        int wbase = 0;
        for (int i = 0; i < wv; i++) wbase += wsum[i];
        int excl = wbase + incl - v;
        lb[tid] = excl;
        cur[tid] = excl;
        if (tid < NB && v > 0) gbase[tid] = atomicAdd(&gcnt[p * NB + tid], v);
        __syncthreads();
        // LDS reorder by bucket
#pragma unroll
        for (int j = 0; j < 16; j++)
            if (bkt[j] >= 0) {
                int r = atomicAdd(&cur[bkt[j]], 1);
                stage[r] = word[j];
            }
        __syncthreads();
        // bucket-contiguous write out
        for (int s = tid; s < total; s += 256) {
            unsigned int wd = stage[s];
            int b = wd >> 24;
            int posl = gbase[b] + (s - lb[b]);
            if (posl < CAP)
                binned[(size_t)(p * NB + b) * CAP + posl] = wd & 0x00FFFFFFu;
        }
        return;
    }
    // ---- converts ----
    int i = (bx - BIN_BLOCKS) * 256 + tid;
    if (i < XP_OCT) {
        f16x8 o;
        if (i < X_OCT) {
            const float4* src = (const float4*)x + (size_t)i * 2;
            float4 v0 = src[0], v1 = src[1];
            o[0] = (_Float16)v0.x; o[1] = (_Float16)v0.y; o[2] = (_Float16)v0.z; o[3] = (_Float16)v0.w;
            o[4] = (_Float16)v1.x; o[5] = (_Float16)v1.y; o[6] = (_Float16)v1.z; o[7] = (_Float16)v1.w;
        } else {
#pragma unroll
            for (int t = 0; t < 8; t++) o[t] = (_Float16)0.0f;  // zero pad rows
        }
        *((f16x8*)xh + i) = o;
    } else if (i < XP_OCT + W_OCT) {
        int j = i - XP_OCT;                // (p, n, k-octet)
        int p   = j / (DD * DD / 8);
        int rem = j - p * (DD * DD / 8);
        int n   = rem >> 5;
        int k8  = (rem & 31) * 8;
        const float* wp = Ws + (size_t)p * DD * DD;
        f16x8 o;
#pragma unroll
        for (int t = 0; t < 8; t++) o[t] = (_Float16)wp[(size_t)(k8 + t) * DD + n];
        *((f16x8*)(Wt + (size_t)p * DD * DD + (size_t)n * DD + k8)) = o;
    } else if (i < XP_OCT + W_OCT + W1_OCT) {
        int j = i - XP_OCT - W_OCT;        // (n, k-octet)
        int n  = j >> 5;
        int k8 = (j & 31) * 8;
        f16x8 o;
#pragma unroll
        for (int t = 0; t < 8; t++) o[t] = (_Float16)w1[(size_t)(k8 + t) * HH + n];
        *((f16x8*)(w1t + (size_t)n * DD + k8)) = o;
    }
}

// ---------------- k_sort (pass 2): per-bucket LDS counting sort -------------
// CSR rows are PADDED to a multiple of 8 edges with PADIDX (zero row), so the
// gather kernel has no scalar tail. offs/ends use exclusive scan of padded
// degrees; dinv uses the real degree.
__global__ __launch_bounds__(256) void k_sort(const int* __restrict__ gcnt,
                                              const unsigned int* __restrict__ binned,
                                              unsigned short* __restrict__ srcs,
                                              int* __restrict__ offs,
                                              int* __restrict__ ends,
                                              float* __restrict__ dinv) {
    __shared__ int hist[256], cur[256], wsum[4];
    __shared__ unsigned short sorted[SCAP];
    const int bx = blockIdx.x;            // p*NB + b
    const int tid = threadIdx.x;
    const int p = bx / NB, b = bx - p * NB;
    const int base = bx * SCAP;
    const int n = min(gcnt[bx], CAP);
    hist[tid] = 0;
#pragma unroll
    for (int j = 0; j < SCAP / 256; j++) sorted[j * 256 + tid] = (unsigned short)PADIDX;
    __syncthreads();
    unsigned int w[20];                   // CAP/256 = 20
#pragma unroll
    for (int j = 0; j < 20; j++) {
        int s = j * 256 + tid;
        w[j] = 0xFFFFFFFFu;
        if (s < n) {
            w[j] = binned[(size_t)bx * CAP + s];
            atomicAdd(&hist[(w[j] >> 16) & 255], 1);
        }
    }
    __syncthreads();
    const int lane = tid & 63, wv = tid >> 6;
    int v  = hist[tid];                   // real degree
    int pv = (v + 7) & ~7;                // padded degree
    int incl = pv;
#pragma unroll
    for (int off = 1; off < 64; off <<= 1) {
        int u = __shfl_up(incl, off);
        if (lane >= off) incl += u;
    }
    if (lane == 63) wsum[wv] = incl;
    __syncthreads();
    int wbase = 0;
    for (int i = 0; i < wv; i++) wbase += wsum[i];
    int excl = wbase + incl - pv;         // exclusive scan of padded degrees
    cur[tid] = excl;
    const int node = b * 256 + tid;
    if (node < NN) {
        int o = base + excl;
        offs[p * NN + node] = o;
        ends[p * NN + node] = o + pv;     // padded end; slots [v,pv) hold PADIDX
        dinv[p * NN + node] = rsqrtf((float)v + 1.0f);
    }
    __syncthreads();
    int totalpad = wsum[0] + wsum[1] + wsum[2] + wsum[3];
#pragma unroll
    for (int j = 0; j < 20; j++)
        if (w[j] != 0xFFFFFFFFu) {
            int r = atomicAdd(&cur[(w[j] >> 16) & 255], 1);
            if (r < SCAP) sorted[r] = (unsigned short)(w[j] & 0xFFFFu);
        }
    __syncthreads();
#pragma unroll
    for (int j = 0; j < SCAP / 256; j++) {
        int s = j * 256 + tid;
        if (s < totalpad && s < SCAP) srcs[base + s] = sorted[s];
    }
}

// ---------------- k_gemm: xws = f16(dinv * (xh @ W)), all MPAD rows ---------
// Rows >= NN get d=0 -> exact zero rows (PADIDX target for padded gathers).
__global__ __launch_bounds__(256) void k_gemm(const _Float16* __restrict__ xh,  // [MPAD][256]
                                              const _Float16* __restrict__ Wt,  // [NP][256 n][256 k]
                                              const float* __restrict__ dinv,   // [NP][NN]
                                              _Float16* __restrict__ xws) {     // [NP][MPAD][256]
    const int gb   = blockIdx.x;
    const int p    = gb / (MPAD / 64);
    const int bm   = gb - p * (MPAD / 64);
    const int wv   = threadIdx.x >> 6;
    const int lane = threadIdx.x & 63;
    const int m_base = bm * 64;
    const int n0   = wv * 64;
    const int mr   = lane & 15;
    const int quad = lane >> 4;

    const _Float16* ap = xh + (size_t)(m_base + mr) * DD + quad * 8;
    const _Float16* bp = Wt + (size_t)p * DD * DD + (size_t)(n0 + mr) * DD + quad * 8;
    const float* dv = dinv + (size_t)p * NN;
    _Float16* cp = xws + (size_t)p * MPAD * DD;

    f32x4 acc[4][4] = {};   // [m-tile][n-tile]
    for (int k0 = 0; k0 < DD; k0 += 32) {
        f16x8 a[4], b[4];
#pragma unroll
        for (int i = 0; i < 4; i++) a[i] = *(const f16x8*)(ap + (size_t)i * 16 * DD + k0);
#pragma unroll
        for (int j = 0; j < 4; j++) b[j] = *(const f16x8*)(bp + (size_t)j * 16 * DD + k0);
#pragma unroll
        for (int i = 0; i < 4; i++)
#pragma unroll
            for (int j = 0; j < 4; j++)
                acc[i][j] = __builtin_amdgcn_mfma_f32_16x16x32_f16(a[i], b[j], acc[i][j], 0, 0, 0);
    }
#pragma unroll
    for (int i = 0; i < 4; i++) {
#pragma unroll
        for (int r = 0; r < 4; r++) {
            int row = m_base + i * 16 + quad * 4 + r;
            float d = (row < NN) ? dv[row] : 0.0f;
#pragma unroll
            for (int j = 0; j < 4; j++)
                cp[(size_t)row * DD + n0 + j * 16 + mr] = (_Float16)(d * acc[i][j][r]);
        }
    }
}

// ---------------- fused gather + bias + MFMA semantic attention -------------
// 512 threads = 8 waves; block handles 16 nodes (64 z-rows in LDS, 33.8 KB).
// CSR rows are multiples of 8 edges (PADIDX-padded): branchless 16-edge main
// step with 8 row-loads in flight per lane, at most one 8-edge step, no tail.
__global__ __launch_bounds__(512) void k_fused(const _Float16* __restrict__ xws, // [NP][MPAD][256]
                                               const float* __restrict__ dinv,   // [NP][NN]
                                               const int* __restrict__ offs,     // [NP][NN]
                                               const int* __restrict__ ends,     // [NP][NN] padded
                                               const unsigned short* __restrict__ srcs,
                                               const float* __restrict__ bs,     // [NP][256]
                                               const _Float16* __restrict__ w1t, // [128 n][256 k]
                                               const float* __restrict__ b1,     // [128]
                                               const float* __restrict__ w2,     // [128]
                                               float* __restrict__ out) {        // [NN][256]
    const int w    = threadIdx.x >> 6;   // 0..7
    const int lane = threadIdx.x & 63;
    const int quad = lane >> 4, mr = lane & 15;
    const int half = lane >> 5, hl = lane & 31;

    // row stride 264 halves = 528 B keeps f16x8 accesses 16B-aligned.
    __shared__ __align__(16) _Float16 zs[64][264];

    union U { f16x8 v; int i4[4]; };

    // ---- gather: z[row] = dinv*(self + sum_src xws[src]) + bias
#pragma unroll 1
    for (int q = 0; q < 2; q++) {
        const int n = blockIdx.x * 16 + w * 2 + q;
#pragma unroll 1
        for (int p = 0; p < NP; p++) {
            const _Float16* xp = xws + (size_t)p * MPAD * DD;
            U acc;
#pragma unroll
            for (int t = 0; t < 4; t++) acc.i4[t] = 0;
            if (half == 0)
                acc.v = *(const f16x8*)(xp + (size_t)n * DD + hl * 8);  // self loop
            int k  = offs[p * NN + n];
            int ke = ends[p * NN + n];
            // 16-edge steps: 8 independent row loads in flight per lane
            for (; k + 16 <= ke; k += 16) {
                int s[8];
#pragma unroll
                for (int j = 0; j < 8; j++) s[j] = srcs[k + 2 * j + half];
                f16x8 v[8];
#pragma unroll
                for (int j = 0; j < 8; j++)
                    v[j] = *(const f16x8*)(xp + (size_t)s[j] * DD + hl * 8);
                acc.v += ((v[0] + v[1]) + (v[2] + v[3])) + ((v[4] + v[5]) + (v[6] + v[7]));
            }
            if (k < ke) {   // exactly 8 remaining
                int s[4];
#pragma unroll
                for (int j = 0; j < 4; j++) s[j] = srcs[k + 2 * j + half];
                f16x8 v[4];
#pragma unroll
                for (int j = 0; j < 4; j++)
                    v[j] = *(const f16x8*)(xp + (size_t)s[j] * DD + hl * 8);
                acc.v += (v[0] + v[1]) + (v[2] + v[3]);
            }
            // combine even/odd halves
            U other;
#pragma unroll
            for (int t = 0; t < 4; t++) other.i4[t] = __shfl_xor(acc.i4[t], 32);
            acc.v += other.v;
            if (half == 0) {
                float dvv = dinv[p * NN + n];
                int row = (w * 2 + q) * 4 + p;
                f16x8 zo;
#pragma unroll
                for (int t = 0; t < 8; t++)
                    zo[t] = (_Float16)(dvv * (float)acc.v[t] + bs[p * DD + hl * 8 + t]);
                *(f16x8*)&zs[row][hl * 8] = zo;
            }
        }
    }

    __syncthreads();
    if (w >= 4) return;   // attention/combine handled by waves 0-3

    // ---- attention MFMA: H(16x128) = Z_rows(16x256) @ w1t(128x256)^T per wave
    f32x4 acch[8] = {};
    for (int k0 = 0; k0 < DD; k0 += 32) {
        f16x8 a = *(const f16x8*)&zs[w * 16 + mr][k0 + quad * 8];
#pragma unroll
        for (int j = 0; j < 8; j++) {
            f16x8 b = *(const f16x8*)(w1t + (size_t)(j * 16 + mr) * DD + k0 + quad * 8);
            acch[j] = __builtin_amdgcn_mfma_f32_16x16x32_f16(a, b, acch[j], 0, 0, 0);
        }
    }

    // ---- scores: s[path] = sum_col tanh(h + b1[col]) * w2[col]
    float part[4] = {};
#pragma unroll
    for (int j = 0; j < 8; j++) {
        int col = j * 16 + mr;
        float bb = b1[col], ww = w2[col];
#pragma unroll
        for (int r = 0; r < 4; r++)
            part[r] += tanhf(acch[j][r] + bb) * ww;
    }
#pragma unroll
    for (int off = 1; off < 16; off <<= 1) {
#pragma unroll
        for (int r = 0; r < 4; r++) part[r] += __shfl_xor(part[r], off);
    }
    float m = fmaxf(fmaxf(part[0], part[1]), fmaxf(part[2], part[3]));
    float e0 = __expf(part[0] - m), e1 = __expf(part[1] - m),
          e2 = __expf(part[2] - m), e3 = __expf(part[3] - m);
    float rr = 1.0f / (e0 + e1 + e2 + e3);
    float be[4] = {e0 * rr, e1 * rr, e2 * rr, e3 * rr};

    // ---- combine: lane handles node (w*4+quad), cols [mr*16, mr*16+16)
    const int n  = blockIdx.x * 16 + w * 4 + quad;
    const int rb = w * 16 + quad * 4;
    float o[16] = {};
#pragma unroll
    for (int p = 0; p < 4; p++) {
        f16x8 z0 = *(const f16x8*)&zs[rb + p][mr * 16];
        f16x8 z1 = *(const f16x8*)&zs[rb + p][mr * 16 + 8];
#pragma unroll
        for (int t = 0; t < 8; t++) {
            o[t]     += be[p] * (float)z0[t];
            o[t + 8] += be[p] * (float)z1[t];
        }
    }
#pragma unroll
    for (int t = 0; t < 16; t += 4)
        *(float4*)(out + (size_t)n * DD + mr * 16 + t) =
            make_float4(o[t], o[t + 1], o[t + 2], o[t + 3]);
}

extern "C" void kernel_launch(void* const* d_in, const int* in_sizes, int n_in,
                              void* d_out, int out_size, void* d_ws, size_t ws_size,
                              hipStream_t stream) {
    const float* x     = (const float*)d_in[0];
    const int*   edges = (const int*)d_in[1];   // [4][2][800000]
    const float* Ws    = (const float*)d_in[2]; // [4][256][256]
    const float* bs    = (const float*)d_in[3]; // [4][256]
    const float* w1    = (const float*)d_in[4]; // [256][128]
    const float* b1    = (const float*)d_in[5]; // [128]
    const float* w2    = (const float*)d_in[6]; // [128]
    float* out = (float*)d_out;

    char* ws = (char*)d_ws;
    int*            gcnt   = (int*)ws;                          // 3.1 KB
    unsigned int*   binned = (unsigned int*)(ws + (1 << 20));   // 784*5120*4 = 16.06 MB
    unsigned short* srcs   = (unsigned short*)(ws + (18 << 20));// 784*6144*2 = 9.63 MB
    float*          dinv   = (float*)(ws + (28 << 20));         // 800 KB
    int*            offs   = (int*)(ws + (29 << 20));           // 800 KB
    int*            ends   = (int*)(ws + (30 << 20));           // 800 KB
    _Float16*       Wt     = (_Float16*)(ws + (31 << 20));      // 512 KB
    _Float16*       w1t    = (_Float16*)(ws + (31 << 20) + (1 << 19)); // 64 KB
    _Float16*       xh     = (_Float16*)(ws + (32 << 20));      // 25.6 MB (MPAD rows)
    _Float16*       xws    = (_Float16*)(ws + (58 << 20));      // 102.5 MB (MPAD rows) -> ~161 MB

    hipMemsetAsync(gcnt, 0, NP * NB * sizeof(int), stream);

    k_bin<<<BIN_BLOCKS + CVT_BLOCKS, 256, 0, stream>>>(
        edges, gcnt, binned, x, Ws, w1, xh, Wt, w1t);

    k_sort<<<NP * NB, 256, 0, stream>>>(gcnt, binned, srcs, offs, ends, dinv);

    k_gemm<<<GEMM_BLOCKS, 256, 0, stream>>>(xh, Wt, dinv, xws);

    k_fused<<<NN / 16, 512, 0, stream>>>(xws, dinv, offs, ends, srcs,
                                         bs, w1t, b1, w2, out);
}